// Round 12
// baseline (731.144 us; speedup 1.0000x reference)
//
#include <hip/hip_runtime.h>
#include <math.h>

constexpr int FDIM = 128;   // IN == HID
constexpr int ODIM = 64;    // NC
constexpr int BINB = 512;   // binning blocks per graph
constexpr int NBK  = 256;   // max buckets (256 nodes each -> N <= 65536)
constexpr int CSB  = 512;   // colstats blocks

typedef short bf16x8 __attribute__((ext_vector_type(8)));   // 8 bf16 in 4 VGPRs
typedef float f32x4  __attribute__((ext_vector_type(4)));

// bf16 helpers (RNE pack, bit-shift unpack)
__device__ inline unsigned short f2bf(float f) {
    unsigned u = __float_as_uint(f);
    u = (u + 0x7fffu + ((u >> 16) & 1u)) >> 16;
    return (unsigned short)u;
}
__device__ inline float bf2f(unsigned short s) { return __uint_as_float(((unsigned)s) << 16); }
__device__ inline float blo(unsigned v) { return __uint_as_float(v << 16); }
__device__ inline float bhi(unsigned v) { return __uint_as_float(v & 0xffff0000u); }

// ---------------- column stats, C=128 (f32 in, optional bf16 emit), 512x256 ----------------
__global__ __launch_bounds__(256) void k_cs128(const float* __restrict__ X, int N,
                                               float* __restrict__ partial,
                                               unsigned short* __restrict__ XB) {
    const int t = threadIdx.x;
    const int rh = t >> 7, c = t & 127;
    const int rows_per = (N + gridDim.x - 1) / gridDim.x;
    const int r0 = blockIdx.x * rows_per;
    const int r1 = min(N, r0 + rows_per);
    float s = 0.f, ss = 0.f;
    for (int r = r0 + rh; r < r1; r += 2) {
        const float v = X[(size_t)r * 128 + c];
        s += v;
        ss += v * v;
        if (XB) XB[(size_t)r * 128 + c] = f2bf(v);
    }
    __shared__ float shs[256], shss[256];
    shs[t] = s;
    shss[t] = ss;
    __syncthreads();
    if (rh == 0) {
        partial[(size_t)blockIdx.x * 256 + c]       = s + shs[t + 128];
        partial[(size_t)blockIdx.x * 256 + 128 + c] = ss + shss[t + 128];
    }
}

// bf16-input variant (for Hb)
__global__ __launch_bounds__(256) void k_cs128b(const unsigned short* __restrict__ X, int N,
                                                float* __restrict__ partial) {
    const int t = threadIdx.x;
    const int rh = t >> 7, c = t & 127;
    const int rows_per = (N + gridDim.x - 1) / gridDim.x;
    const int r0 = blockIdx.x * rows_per;
    const int r1 = min(N, r0 + rows_per);
    float s = 0.f, ss = 0.f;
    for (int r = r0 + rh; r < r1; r += 2) {
        const float v = bf2f(X[(size_t)r * 128 + c]);
        s += v;
        ss += v * v;
    }
    __shared__ float shs[256], shss[256];
    shs[t] = s;
    shss[t] = ss;
    __syncthreads();
    if (rh == 0) {
        partial[(size_t)blockIdx.x * 256 + c]       = s + shs[t + 128];
        partial[(size_t)blockIdx.x * 256 + 128 + c] = ss + shss[t + 128];
    }
}

// C=64 f32 variant (for Z)
__global__ __launch_bounds__(256) void k_cs64(const float* __restrict__ X, int N,
                                              float* __restrict__ partial) {
    const int t = threadIdx.x;
    const int rh = t >> 6, c = t & 63;       // 4 rows x 64 cols
    const int rows_per = (N + gridDim.x - 1) / gridDim.x;
    const int r0 = blockIdx.x * rows_per;
    const int r1 = min(N, r0 + rows_per);
    float s = 0.f, ss = 0.f;
    for (int r = r0 + rh; r < r1; r += 4) {
        const float v = X[(size_t)r * 64 + c];
        s += v;
        ss += v * v;
    }
    __shared__ float shs[256], shss[256];
    shs[t] = s;
    shss[t] = ss;
    __syncthreads();
    if (rh == 0) {
        partial[(size_t)blockIdx.x * 128 + c] =
            s + shs[t + 64] + shs[t + 128] + shs[t + 192];
        partial[(size_t)blockIdx.x * 128 + 64 + c] =
            ss + shss[t + 64] + shss[t + 128] + shss[t + 192];
    }
}

template<int C>
__global__ void k_colstats_fin(const float* __restrict__ partial, int nb, int N,
                               const float* __restrict__ gamma, const float* __restrict__ beta,
                               float* __restrict__ scale, float* __restrict__ shift) {
    const int c = threadIdx.x;          // blockDim.x == C
    float s = 0.f, ss = 0.f;
    for (int b = 0; b < nb; ++b) {
        s  += partial[(size_t)b * (2 * C) + c];
        ss += partial[(size_t)b * (2 * C) + C + c];
    }
    const float mu  = s / (float)N;
    const float var = ss / (float)N - mu * mu;
    const float sc  = gamma[c] * rsqrtf(var + 1e-5f);
    scale[c] = sc;
    shift[c] = beta[c] - mu * sc;
}

// ---------------- weights -> bf16 transposed: WTb[g][n][k] = bf16(Wg[k][n]) (layer1) ----------------
__global__ void k_wt(const float* __restrict__ W1, const float* __restrict__ W2,
                     const float* __restrict__ W3, unsigned short* __restrict__ WTb) {
    const int g = blockIdx.y;
    const float* W = (g == 0) ? W1 : (g == 1) ? W2 : W3;
    const int id = blockIdx.x * 256 + threadIdx.x;   // 0..16383
    const int n = id >> 7, k = id & 127;
    WTb[(size_t)g * 16384 + (size_t)n * 128 + k] = f2bf(W[(size_t)k * 128 + n]);
}

// ---------------- layer2 weights: W2Tb[g][n][k] = bf16(s2[k] * Wg2[k][n]) ----------------
__global__ void k_wt2(const float* __restrict__ s2,
                      const float* __restrict__ W1, const float* __restrict__ W2,
                      const float* __restrict__ W3, unsigned short* __restrict__ W2Tb) {
    const int g = blockIdx.y;
    const float* W = (g == 0) ? W1 : (g == 1) ? W2 : W3;
    const int id = blockIdx.x * 256 + threadIdx.x;   // 0..8191
    const int n = id >> 7, k = id & 127;
    W2Tb[(size_t)g * 8192 + (size_t)n * 128 + k] = f2bf(s2[k] * W[(size_t)k * ODIM + n]);
}

// ================= CSR build via bucket binning (single-writer nbr lines) =================
__global__ __launch_bounds__(256) void k_bincount(
    const int* __restrict__ d0, const int* __restrict__ d1, const int* __restrict__ d2,
    int e0, int e1, int e2, unsigned* __restrict__ cnts) {
    const int g = blockIdx.y, blk = blockIdx.x, t = threadIdx.x;
    const int* dst = (g == 0) ? d0 : (g == 1) ? d1 : d2;
    const int E = (g == 0) ? e0 : (g == 1) ? e1 : e2;
    __shared__ unsigned hist[NBK];
    hist[t] = 0;
    __syncthreads();
    const int chunk = (E + BINB - 1) / BINB;
    const int i0 = blk * chunk, i1 = min(E, i0 + chunk);
    for (int i = i0 + t; i < i1; i += 256) atomicAdd(&hist[((unsigned)dst[i]) >> 8], 1u);
    __syncthreads();
    cnts[((size_t)(g * NBK + t)) * BINB + blk] = hist[t];
}

__global__ __launch_bounds__(256) void k_sa(const unsigned* __restrict__ cnts,
                                            unsigned* __restrict__ bs) {
    const int blk = blockIdx.x, t = threadIdx.x;
    unsigned s = cnts[(size_t)blk * 512 + t] + cnts[(size_t)blk * 512 + 256 + t];
    __shared__ unsigned red[256];
    red[t] = s;
    __syncthreads();
    for (int o = 128; o; o >>= 1) {
        if (t < o) red[t] += red[t + o];
        __syncthreads();
    }
    if (t == 0) bs[blk] = red[0];
}

__global__ void k_sb(unsigned* __restrict__ bs, int n) {
    const int t = threadIdx.x;
    __shared__ unsigned ps[1024];
    unsigned v = (t < n) ? bs[t] : 0u;
    ps[t] = v;
    __syncthreads();
    for (int o = 1; o < 1024; o <<= 1) {
        const unsigned a = (t >= o) ? ps[t - o] : 0u;
        __syncthreads();
        ps[t] += a;
        __syncthreads();
    }
    if (t < n) bs[t] = ps[t] - v;
}

__global__ __launch_bounds__(256) void k_sc(unsigned* __restrict__ cnts,
                                            const unsigned* __restrict__ bs) {
    const int blk = blockIdx.x, t = threadIdx.x;
    const size_t base = (size_t)blk * 512;
    const unsigned e0v = cnts[base + 2 * t];
    const unsigned e1v = cnts[base + 2 * t + 1];
    const unsigned pair = e0v + e1v;
    __shared__ unsigned ps[256];
    ps[t] = pair;
    __syncthreads();
    for (int o = 1; o < 256; o <<= 1) {
        const unsigned a = (t >= o) ? ps[t - o] : 0u;
        __syncthreads();
        ps[t] += a;
        __syncthreads();
    }
    const unsigned ex = ps[t] - pair + bs[blk];
    cnts[base + 2 * t]     = ex;
    cnts[base + 2 * t + 1] = ex + e0v;
}

__global__ __launch_bounds__(256) void k_binplace(
    const int* __restrict__ s0, const int* __restrict__ d0,
    const int* __restrict__ s1, const int* __restrict__ d1,
    const int* __restrict__ s2, const int* __restrict__ d2,
    int e0, int e1, int e2, const unsigned* __restrict__ pos, int2* __restrict__ ebuf) {
    const int g = blockIdx.y, blk = blockIdx.x, t = threadIdx.x;
    const int* src = (g == 0) ? s0 : (g == 1) ? s1 : s2;
    const int* dst = (g == 0) ? d0 : (g == 1) ? d1 : d2;
    const int E = (g == 0) ? e0 : (g == 1) ? e1 : e2;
    __shared__ unsigned cur[NBK];
    cur[t] = pos[((size_t)(g * NBK + t)) * BINB + blk];
    __syncthreads();
    const int chunk = (E + BINB - 1) / BINB;
    const int i0 = blk * chunk, i1 = min(E, i0 + chunk);
    for (int i = i0 + t; i < i1; i += 256) {
        const int dv = dst[i];
        const unsigned p = atomicAdd(&cur[((unsigned)dv) >> 8], 1u);
        ebuf[p] = make_int2(src[i], dv);
    }
}

__global__ __launch_bounds__(256) void k_build(
    const int2* __restrict__ ebuf, const unsigned* __restrict__ pos,
    int etot, int e0, int e1,
    int* __restrict__ off, int* __restrict__ cend, float* __restrict__ rinv,
    int* __restrict__ n0, int* __restrict__ n1, int* __restrict__ n2, int N) {
    const int g = blockIdx.y, b = blockIdx.x, t = threadIdx.x;
    const int v0 = b << 8;
    const int gbase = (g == 0) ? 0 : ((g == 1) ? e0 : e0 + e1);
    int* nbr = (g == 0) ? n0 : ((g == 1) ? n1 : n2);
    const int cell = g * NBK + b;
    const unsigned seg0 = pos[(size_t)cell * BINB];
    const unsigned seg1 = (cell + 1 < 3 * NBK) ? pos[(size_t)(cell + 1) * BINB] : (unsigned)etot;

    __shared__ unsigned deg[NBK];
    __shared__ unsigned ps[NBK];
    __shared__ unsigned cur[NBK];
    deg[t] = 0;
    __syncthreads();
    for (unsigned i = seg0 + t; i < seg1; i += 256) atomicAdd(&deg[ebuf[i].y - v0], 1u);
    __syncthreads();
    const unsigned dv = deg[t];
    ps[t] = dv;
    __syncthreads();
    for (int o = 1; o < 256; o <<= 1) {
        const unsigned a = (t >= o) ? ps[t - o] : 0u;
        __syncthreads();
        ps[t] += a;
        __syncthreads();
    }
    const unsigned ex = ps[t] - dv;     // exclusive within bucket
    const int nbase = (int)seg0 - gbase;
    const int node = v0 + t;
    if (node < N) {
        off[(size_t)g * N + node]  = nbase + (int)ex;
        cend[(size_t)g * N + node] = nbase + (int)(ex + dv);
        rinv[(size_t)g * N + node] = 1.0f / ((float)dv + 1.0f);
    }
    cur[t] = ex;
    __syncthreads();
    for (unsigned i = seg0 + t; i < seg1; i += 256) {
        const int2 e = ebuf[i];
        const unsigned p = atomicAdd(&cur[e.y - v0], 1u);
        nbr[nbase + (int)p] = e.x;
    }
}

// ---------------- gather (bf16 x rows, 3 graphs via blockIdx.y), BN1 fused, bf16 out ----------------
__global__ __launch_bounds__(256) void k_gather3(
    const unsigned short* __restrict__ XB,
    const int* __restrict__ nbr0, const int* __restrict__ nbr1, const int* __restrict__ nbr2,
    const int* __restrict__ off, const int* __restrict__ cend,
    const float* __restrict__ rinv, const float* __restrict__ s1,
    const float* __restrict__ sh1, unsigned short* __restrict__ AGG3b, int N) {
    const int g = blockIdx.y;
    const int* nbr = (g == 0) ? nbr0 : (g == 1) ? nbr1 : nbr2;
    const int gb = g * N;
    const int wave = threadIdx.x >> 6;
    const int lane = threadIdx.x & 63;
    const int v = blockIdx.x * 4 + wave;
    if (v >= N) return;
    const int i0 = off[gb + v], i1 = cend[gb + v];
    const int l2 = lane * 2;
    unsigned sv = ((const unsigned*)(XB + (size_t)v * FDIM))[lane];
    float2 acc;
    acc.x = blo(sv);
    acc.y = bhi(sv);
    int i = i0;
    for (; i + 8 <= i1; i += 8) {
        const int u0 = nbr[i],     u1 = nbr[i + 1], u2 = nbr[i + 2], u3 = nbr[i + 3];
        const int u4 = nbr[i + 4], u5 = nbr[i + 5], u6 = nbr[i + 6], u7 = nbr[i + 7];
        const unsigned a0 = ((const unsigned*)(XB + (size_t)u0 * FDIM))[lane];
        const unsigned a1 = ((const unsigned*)(XB + (size_t)u1 * FDIM))[lane];
        const unsigned a2 = ((const unsigned*)(XB + (size_t)u2 * FDIM))[lane];
        const unsigned a3 = ((const unsigned*)(XB + (size_t)u3 * FDIM))[lane];
        const unsigned a4 = ((const unsigned*)(XB + (size_t)u4 * FDIM))[lane];
        const unsigned a5 = ((const unsigned*)(XB + (size_t)u5 * FDIM))[lane];
        const unsigned a6 = ((const unsigned*)(XB + (size_t)u6 * FDIM))[lane];
        const unsigned a7 = ((const unsigned*)(XB + (size_t)u7 * FDIM))[lane];
        acc.x += ((blo(a0) + blo(a1)) + (blo(a2) + blo(a3))) + ((blo(a4) + blo(a5)) + (blo(a6) + blo(a7)));
        acc.y += ((bhi(a0) + bhi(a1)) + (bhi(a2) + bhi(a3))) + ((bhi(a4) + bhi(a5)) + (bhi(a6) + bhi(a7)));
    }
    for (; i < i1; ++i) {
        const unsigned a = ((const unsigned*)(XB + (size_t)nbr[i] * FDIM))[lane];
        acc.x += blo(a);
        acc.y += bhi(a);
    }
    const float r = rinv[gb + v];
    const float2 sc = *(const float2*)&s1[l2];
    const float2 sh = *(const float2*)&sh1[l2];
    const float ox = fmaf(acc.x * r, sc.x, sh.x);
    const float oy = fmaf(acc.y * r, sc.y, sh.y);
    const unsigned w = (unsigned)f2bf(ox) | ((unsigned)f2bf(oy) << 16);
    ((unsigned*)(AGG3b + ((size_t)(gb + v)) * FDIM))[lane] = w;
}

// ---------------- GEMM1 (MFMA bf16): Hb = bf16(relu( [A0|A1|A2] @ [W1;W2;W3] + sum b )) ----------------
__global__ __launch_bounds__(256) void k_gemm1(
    const unsigned short* __restrict__ AGG3b, const unsigned short* __restrict__ WTb,
    const float* __restrict__ b1, const float* __restrict__ b2, const float* __restrict__ b3,
    unsigned short* __restrict__ Hb, int N) {
    constexpr int AST = 40;                 // padded row stride in shorts (80 B, 16B-aligned)
    __shared__ __align__(16) unsigned short As[64 * AST];
    __shared__ __align__(16) unsigned short Bs[128 * AST];
    const int t = threadIdx.x;
    const int w = t >> 6, l = t & 63;
    const int row0 = blockIdx.x * 64;
    const int cl = l & 15;
    const int hi = l >> 4;
    f32x4 acc[8] = {};

    for (int g = 0; g < 3; ++g) {
        const unsigned short* Ag = AGG3b + (size_t)g * N * FDIM;
        const unsigned short* Wg = WTb + (size_t)g * 16384;
        for (int kb = 0; kb < 4; ++kb) {
            const int k0 = kb * 32;
            {
                const int r = t >> 2, h = t & 3;
                const int row = row0 + r;
                uint4 v = make_uint4(0u, 0u, 0u, 0u);
                if (row < N) v = *(const uint4*)(Ag + (size_t)row * FDIM + k0 + h * 8);
                *(uint4*)(As + r * AST + h * 8) = v;
            }
            {
                const int c = t >> 1, p = t & 1;
                const uint4 v0 = *(const uint4*)(Wg + (size_t)c * 128 + k0 + p * 16);
                const uint4 v1 = *(const uint4*)(Wg + (size_t)c * 128 + k0 + p * 16 + 8);
                *(uint4*)(Bs + c * AST + p * 16)     = v0;
                *(uint4*)(Bs + c * AST + p * 16 + 8) = v1;
            }
            __syncthreads();
            const bf16x8 af = *(const bf16x8*)(As + (w * 16 + cl) * AST + hi * 8);
            #pragma unroll
            for (int c = 0; c < 8; ++c) {
                const bf16x8 bf = *(const bf16x8*)(Bs + (c * 16 + cl) * AST + hi * 8);
                acc[c] = __builtin_amdgcn_mfma_f32_16x16x32_bf16(af, bf, acc[c], 0, 0, 0);
            }
            __syncthreads();
        }
    }
    #pragma unroll
    for (int c = 0; c < 8; ++c) {
        const int col = c * 16 + cl;
        const float bb = b1[col] + b2[col] + b3[col];
        #pragma unroll
        for (int r = 0; r < 4; ++r) {
            const int row = row0 + w * 16 + hi * 4 + r;
            if (row < N) Hb[(size_t)row * FDIM + col] = f2bf(fmaxf(acc[c][r] + bb, 0.f));
        }
    }
}

// ---------------- c2[g][n] = sum_k sh2[k] * Wg[k][n] ----------------
__global__ void k_c2(const float* __restrict__ sh2,
                     const float* __restrict__ W1, const float* __restrict__ W2,
                     const float* __restrict__ W3, float* __restrict__ c2) {
    const int t = threadIdx.x;   // 192
    const int g = t >> 6, n = t & 63;
    const float* W = (g == 0) ? W1 : (g == 1) ? W2 : W3;
    float s = 0.f;
    for (int k = 0; k < 128; ++k) s = fmaf(sh2[k], W[(size_t)k * ODIM + n], s);
    c2[g * ODIM + n] = s;
}

// ---------------- GEMM2 (MFMA bf16): Ub_g = bf16( Hb @ W2Tb_g + c2_g ), 64x64 tile ----------------
__global__ __launch_bounds__(256) void k_gemm2(
    const unsigned short* __restrict__ Hb, const unsigned short* __restrict__ W2Tb,
    const float* __restrict__ c2, unsigned short* __restrict__ Ub, int N) {
    constexpr int AST = 40;
    __shared__ __align__(16) unsigned short As[64 * AST];
    __shared__ __align__(16) unsigned short Bs[64 * AST];
    const int t = threadIdx.x;
    const int g = blockIdx.y;
    const int w = t >> 6, l = t & 63;
    const int row0 = blockIdx.x * 64;
    const int cl = l & 15;
    const int hi = l >> 4;
    const unsigned short* Wg = W2Tb + (size_t)g * 8192;
    f32x4 acc[4] = {};

    for (int kb = 0; kb < 4; ++kb) {
        const int k0 = kb * 32;
        {
            const int r = t >> 2, h = t & 3;
            const int row = row0 + r;
            uint4 v = make_uint4(0u, 0u, 0u, 0u);
            if (row < N) v = *(const uint4*)(Hb + (size_t)row * FDIM + k0 + h * 8);
            *(uint4*)(As + r * AST + h * 8) = v;
        }
        {
            const int c = t >> 2, h = t & 3;
            const uint4 v = *(const uint4*)(Wg + (size_t)c * 128 + k0 + h * 8);
            *(uint4*)(Bs + c * AST + h * 8) = v;
        }
        __syncthreads();
        const bf16x8 af = *(const bf16x8*)(As + (w * 16 + cl) * AST + hi * 8);
        #pragma unroll
        for (int c = 0; c < 4; ++c) {
            const bf16x8 bf = *(const bf16x8*)(Bs + (c * 16 + cl) * AST + hi * 8);
            acc[c] = __builtin_amdgcn_mfma_f32_16x16x32_bf16(af, bf, acc[c], 0, 0, 0);
        }
        __syncthreads();
    }
    const float* cg = c2 + (size_t)g * ODIM;
    unsigned short* Ug = Ub + (size_t)g * N * ODIM;
    #pragma unroll
    for (int c = 0; c < 4; ++c) {
        const int col = c * 16 + cl;
        const float bb = cg[col];
        #pragma unroll
        for (int r = 0; r < 4; ++r) {
            const int row = row0 + w * 16 + hi * 4 + r;
            if (row < N) Ug[(size_t)row * ODIM + col] = f2bf(acc[c][r] + bb);
        }
    }
}

// ---------------- layer-2 gather + combine (bf16 U rows) ----------------
__global__ __launch_bounds__(256) void k_gc64(
    const unsigned short* __restrict__ Ub,
    const int* __restrict__ nbr0, const int* __restrict__ nbr1, const int* __restrict__ nbr2,
    const int* __restrict__ off, const int* __restrict__ cend,
    const float* __restrict__ rinv,
    const float* __restrict__ b1, const float* __restrict__ b2, const float* __restrict__ b3,
    float* __restrict__ Z, int N) {
    const int wave = threadIdx.x >> 6;
    const int lane = threadIdx.x & 63;
    const int v = blockIdx.x * 4 + wave;
    if (v >= N) return;
    const size_t gs = (size_t)N * ODIM;
    float z = b1[lane] + b2[lane] + b3[lane];
    #pragma unroll
    for (int g = 0; g < 3; ++g) {
        const unsigned short* Ug = Ub + (size_t)g * gs;
        const int* nb = (g == 0) ? nbr0 : (g == 1) ? nbr1 : nbr2;
        const int i0 = off[g * N + v], i1 = cend[g * N + v];
        float s = bf2f(Ug[(size_t)v * ODIM + lane]);
        int i = i0;
        for (; i + 8 <= i1; i += 8) {
            const int u0 = nb[i],     u1 = nb[i + 1], u2 = nb[i + 2], u3 = nb[i + 3];
            const int u4 = nb[i + 4], u5 = nb[i + 5], u6 = nb[i + 6], u7 = nb[i + 7];
            const float a0 = bf2f(Ug[(size_t)u0 * ODIM + lane]);
            const float a1 = bf2f(Ug[(size_t)u1 * ODIM + lane]);
            const float a2 = bf2f(Ug[(size_t)u2 * ODIM + lane]);
            const float a3 = bf2f(Ug[(size_t)u3 * ODIM + lane]);
            const float a4 = bf2f(Ug[(size_t)u4 * ODIM + lane]);
            const float a5 = bf2f(Ug[(size_t)u5 * ODIM + lane]);
            const float a6 = bf2f(Ug[(size_t)u6 * ODIM + lane]);
            const float a7 = bf2f(Ug[(size_t)u7 * ODIM + lane]);
            s += ((a0 + a1) + (a2 + a3)) + ((a4 + a5) + (a6 + a7));
        }
        for (; i < i1; ++i) s += bf2f(Ug[(size_t)nb[i] * ODIM + lane]);
        z += s * rinv[g * N + v];
    }
    Z[(size_t)v * ODIM + lane] = z;
}

// ---------------- final: BN3 + sigmoid + row min-max + row L2, in place ----------------
__global__ __launch_bounds__(256) void k_final(float* __restrict__ Z,
                                               const float* __restrict__ scale,
                                               const float* __restrict__ shift, int N) {
    const int wave = threadIdx.x >> 6;
    const int lane = threadIdx.x & 63;
    const int row = blockIdx.x * 4 + wave;
    if (row >= N) return;
    float v = fmaf(Z[(size_t)row * ODIM + lane], scale[lane], shift[lane]);
    float s = 1.0f / (1.0f + expf(-v));
    float mn = s, mx = s;
    #pragma unroll
    for (int off = 32; off; off >>= 1) {
        mn = fminf(mn, __shfl_xor(mn, off, 64));
        mx = fmaxf(mx, __shfl_xor(mx, off, 64));
    }
    const float sc = (s - mn) / (mx - mn);
    float sq = sc * sc;
    #pragma unroll
    for (int off = 32; off; off >>= 1) sq += __shfl_xor(sq, off, 64);
    const float norm = fmaxf(sqrtf(sq), 1e-12f);
    Z[(size_t)row * ODIM + lane] = sc / norm;
}

extern "C" void kernel_launch(void* const* d_in, const int* in_sizes, int n_in,
                              void* d_out, int out_size, void* d_ws, size_t ws_size,
                              hipStream_t stream) {
    const float* x = (const float*)d_in[0];
    const int* src[3] = {(const int*)d_in[1], (const int*)d_in[3], (const int*)d_in[5]};
    const int* dst[3] = {(const int*)d_in[2], (const int*)d_in[4], (const int*)d_in[6]};
    const int E[3] = {in_sizes[1], in_sizes[3], in_sizes[5]};
    const int Etot = E[0] + E[1] + E[2];
    const float* W11 = (const float*)d_in[7];  const float* b11 = (const float*)d_in[8];
    const float* W21 = (const float*)d_in[9];  const float* b21 = (const float*)d_in[10];
    const float* W31 = (const float*)d_in[11]; const float* b31 = (const float*)d_in[12];
    const float* W12 = (const float*)d_in[13]; const float* b12 = (const float*)d_in[14];
    const float* W22 = (const float*)d_in[15]; const float* b22 = (const float*)d_in[16];
    const float* W32 = (const float*)d_in[17]; const float* b32 = (const float*)d_in[18];
    const float* g1  = (const float*)d_in[19]; const float* be1 = (const float*)d_in[20];
    const float* g2  = (const float*)d_in[21]; const float* be2 = (const float*)d_in[22];
    const float* g3  = (const float*)d_in[23]; const float* be3 = (const float*)d_in[24];
    const int N = in_sizes[0] / FDIM;
    float* Z = (float*)d_out;

    // ---- workspace layout ----
    float* ws   = (float*)d_ws;
    float* Hreg = ws;                          // N*128 f32-sized region
    unsigned short* xb = (unsigned short*)Hreg;   // bf16 N*128 (phase 1)
    unsigned short* Hb = (unsigned short*)Hreg;   // bf16 N*128 (phase 2, after xb dead)
    float* REG  = Hreg + (size_t)N * FDIM;     // 3*N*128 f32-sized region
    unsigned short* AGG3b = (unsigned short*)REG;   // bf16 3*N*128
    unsigned short* Ub = (unsigned short*)REG;      // bf16 3*N*64 (after AGG3b dead)
    int2* ebuf = (int2*)REG;                                   // Etot int2 (pre-gather)
    unsigned* cnts = (unsigned*)(ebuf + (size_t)Etot);         // 3*NBK*BINB
    unsigned* bs   = cnts + (size_t)3 * NBK * BINB;            // 768
    float* rinv = REG + (size_t)3 * N * FDIM;  // 3N
    float* partial = rinv + (size_t)3 * N;     // CSB*256 = 131072
    float* s1  = partial + (size_t)CSB * 256;  float* sh1 = s1 + 128;
    float* s2  = sh1 + 128;        float* sh2 = s2 + 128;
    float* s3  = sh2 + 128;        float* sh3 = s3 + 64;
    float* c2  = sh3 + 64;                     // 3*64
    unsigned short* WTb  = (unsigned short*)(c2 + 3 * ODIM);  // bf16 3*128*128
    unsigned short* W2Tb = WTb + (size_t)3 * 16384;           // bf16 3*64*128
    int* off  = (int*)(W2Tb + (size_t)3 * 8192);          // 3N
    int* cend = off + (size_t)3 * N;                      // 3N
    int* nbr  = cend + (size_t)3 * N;                     // Etot
    int* nbrg[3];
    nbrg[0] = nbr;
    nbrg[1] = nbrg[0] + E[0];
    nbrg[2] = nbrg[1] + E[1];

    // ---- CSR build via bucket binning (single-writer nbr lines) ----
    const int nbuckets = (N + 255) >> 8;
    k_bincount<<<dim3(BINB, 3), 256, 0, stream>>>(dst[0], dst[1], dst[2],
                                                  E[0], E[1], E[2], cnts);
    k_sa<<<3 * NBK * BINB / 512, 256, 0, stream>>>(cnts, bs);
    k_sb<<<1, 1024, 0, stream>>>(bs, 3 * NBK * BINB / 512);
    k_sc<<<3 * NBK * BINB / 512, 256, 0, stream>>>(cnts, bs);
    k_binplace<<<dim3(BINB, 3), 256, 0, stream>>>(src[0], dst[0], src[1], dst[1],
                                                  src[2], dst[2], E[0], E[1], E[2],
                                                  cnts, ebuf);
    k_build<<<dim3(nbuckets, 3), 256, 0, stream>>>(ebuf, cnts, Etot, E[0], E[1],
                                                   off, cend, rinv,
                                                   nbrg[0], nbrg[1], nbrg[2], N);

    // ---- BN1 stats + fused bf16 conversion of x; bf16 transposed layer-1 weights ----
    k_cs128<<<CSB, 256, 0, stream>>>(x, N, partial, xb);
    k_colstats_fin<128><<<1, 128, 0, stream>>>(partial, CSB, N, g1, be1, s1, sh1);
    k_wt<<<dim3(64, 3), 256, 0, stream>>>(W11, W21, W31, WTb);

    // ---- layer 1: 3-graph bf16 gather (bf16 out) -> MFMA K=384 GEMM -> Hb ----
    const int gblocks = (N + 3) / 4;
    k_gather3<<<dim3(gblocks, 3), 256, 0, stream>>>(xb, nbrg[0], nbrg[1], nbrg[2],
                                                    off, cend, rinv, s1, sh1, AGG3b, N);
    k_gemm1<<<(N + 63) / 64, 256, 0, stream>>>(AGG3b, WTb, b11, b21, b31, Hb, N);

    // ---- BN2 stats (from bf16 Hb); scale folded into W2Tb, shift via c2 ----
    k_cs128b<<<CSB, 256, 0, stream>>>(Hb, N, partial);
    k_colstats_fin<128><<<1, 128, 0, stream>>>(partial, CSB, N, g2, be2, s2, sh2);
    k_c2<<<1, 192, 0, stream>>>(sh2, W12, W22, W32, c2);
    k_wt2<<<dim3(32, 3), 256, 0, stream>>>(s2, W12, W22, W32, W2Tb);

    // ---- layer 2: MFMA GEMM (bf16 Ub over dead AGG3b), then bf16 gather+combine ----
    dim3 grid2((N + 63) / 64, 3);
    k_gemm2<<<grid2, 256, 0, stream>>>(Hb, W2Tb, c2, Ub, N);
    k_gc64<<<gblocks, 256, 0, stream>>>(Ub, nbrg[0], nbrg[1], nbrg[2], off, cend, rinv,
                                        b12, b22, b32, Z, N);

    // ---- BN3 + epilogue ----
    k_cs64<<<CSB, 256, 0, stream>>>(Z, N, partial);
    k_colstats_fin<64><<<1, 64, 0, stream>>>(partial, CSB, N, g3, be3, s3, sh3);
    k_final<<<(N + 3) / 4, 256, 0, stream>>>(Z, s3, sh3, N);
}

// Round 13
// 380.057 us; speedup vs baseline: 1.9238x; 1.9238x over previous
//
#include <hip/hip_runtime.h>
#include <math.h>

constexpr int FDIM = 128;   // IN == HID
constexpr int ODIM = 64;    // NC
constexpr int BINB = 512;   // binning blocks per graph
constexpr int NBK  = 256;   // max buckets (256 nodes each -> N <= 65536)
constexpr int CSB  = 512;   // colstats blocks

typedef short bf16x8 __attribute__((ext_vector_type(8)));   // 8 bf16 in 4 VGPRs
typedef float f32x4  __attribute__((ext_vector_type(4)));

// bf16 helpers (RNE pack, bit-shift unpack)
__device__ inline unsigned short f2bf(float f) {
    unsigned u = __float_as_uint(f);
    u = (u + 0x7fffu + ((u >> 16) & 1u)) >> 16;
    return (unsigned short)u;
}
__device__ inline float bf2f(unsigned short s) { return __uint_as_float(((unsigned)s) << 16); }
__device__ inline float blo(unsigned v) { return __uint_as_float(v << 16); }
__device__ inline float bhi(unsigned v) { return __uint_as_float(v & 0xffff0000u); }

// ---------------- column stats, C=128 (f32 in, optional bf16 emit), 512x256 ----------------
__global__ __launch_bounds__(256) void k_cs128(const float* __restrict__ X, int N,
                                               float* __restrict__ partial,
                                               unsigned short* __restrict__ XB) {
    const int t = threadIdx.x;
    const int rh = t >> 7, c = t & 127;
    const int rows_per = (N + gridDim.x - 1) / gridDim.x;
    const int r0 = blockIdx.x * rows_per;
    const int r1 = min(N, r0 + rows_per);
    float s = 0.f, ss = 0.f;
    for (int r = r0 + rh; r < r1; r += 2) {
        const float v = X[(size_t)r * 128 + c];
        s += v;
        ss += v * v;
        if (XB) XB[(size_t)r * 128 + c] = f2bf(v);
    }
    __shared__ float shs[256], shss[256];
    shs[t] = s;
    shss[t] = ss;
    __syncthreads();
    if (rh == 0) {
        partial[(size_t)blockIdx.x * 256 + c]       = s + shs[t + 128];
        partial[(size_t)blockIdx.x * 256 + 128 + c] = ss + shss[t + 128];
    }
}

// bf16-input variant (for Hb)
__global__ __launch_bounds__(256) void k_cs128b(const unsigned short* __restrict__ X, int N,
                                                float* __restrict__ partial) {
    const int t = threadIdx.x;
    const int rh = t >> 7, c = t & 127;
    const int rows_per = (N + gridDim.x - 1) / gridDim.x;
    const int r0 = blockIdx.x * rows_per;
    const int r1 = min(N, r0 + rows_per);
    float s = 0.f, ss = 0.f;
    for (int r = r0 + rh; r < r1; r += 2) {
        const float v = bf2f(X[(size_t)r * 128 + c]);
        s += v;
        ss += v * v;
    }
    __shared__ float shs[256], shss[256];
    shs[t] = s;
    shss[t] = ss;
    __syncthreads();
    if (rh == 0) {
        partial[(size_t)blockIdx.x * 256 + c]       = s + shs[t + 128];
        partial[(size_t)blockIdx.x * 256 + 128 + c] = ss + shss[t + 128];
    }
}

// C=64 f32 variant (for Z)
__global__ __launch_bounds__(256) void k_cs64(const float* __restrict__ X, int N,
                                              float* __restrict__ partial) {
    const int t = threadIdx.x;
    const int rh = t >> 6, c = t & 63;       // 4 rows x 64 cols
    const int rows_per = (N + gridDim.x - 1) / gridDim.x;
    const int r0 = blockIdx.x * rows_per;
    const int r1 = min(N, r0 + rows_per);
    float s = 0.f, ss = 0.f;
    for (int r = r0 + rh; r < r1; r += 4) {
        const float v = X[(size_t)r * 64 + c];
        s += v;
        ss += v * v;
    }
    __shared__ float shs[256], shss[256];
    shs[t] = s;
    shss[t] = ss;
    __syncthreads();
    if (rh == 0) {
        partial[(size_t)blockIdx.x * 128 + c] =
            s + shs[t + 64] + shs[t + 128] + shs[t + 192];
        partial[(size_t)blockIdx.x * 128 + 64 + c] =
            ss + shss[t + 64] + shss[t + 128] + shss[t + 192];
    }
}

// ---------------- parallel stats finalize: one block per channel ----------------
template<int C>
__global__ __launch_bounds__(256) void k_fin(const float* __restrict__ partial, int nb, int N,
                                             const float* __restrict__ gamma,
                                             const float* __restrict__ beta,
                                             float* __restrict__ scale,
                                             float* __restrict__ shift) {
    const int c = blockIdx.x;       // 0..C-1
    const int t = threadIdx.x;      // 256
    float s = 0.f, ss = 0.f;
    for (int b = t; b < nb; b += 256) {
        s  += partial[(size_t)b * (2 * C) + c];
        ss += partial[(size_t)b * (2 * C) + C + c];
    }
    __shared__ float shs[256], shss[256];
    shs[t] = s;
    shss[t] = ss;
    __syncthreads();
    for (int o = 128; o; o >>= 1) {
        if (t < o) { shs[t] += shs[t + o]; shss[t] += shss[t + o]; }
        __syncthreads();
    }
    if (t == 0) {
        const float mu  = shs[0] / (float)N;
        const float var = shss[0] / (float)N - mu * mu;
        const float sc  = gamma[c] * rsqrtf(var + 1e-5f);
        scale[c] = sc;
        shift[c] = beta[c] - mu * sc;
    }
}

// ---------------- weights -> bf16 transposed: WTb[g][n][k] = bf16(Wg[k][n]) (layer1) ----------------
__global__ void k_wt(const float* __restrict__ W1, const float* __restrict__ W2,
                     const float* __restrict__ W3, unsigned short* __restrict__ WTb) {
    const int g = blockIdx.y;
    const float* W = (g == 0) ? W1 : (g == 1) ? W2 : W3;
    const int id = blockIdx.x * 256 + threadIdx.x;   // 0..16383
    const int n = id >> 7, k = id & 127;
    WTb[(size_t)g * 16384 + (size_t)n * 128 + k] = f2bf(W[(size_t)k * 128 + n]);
}

// ---------------- layer2 weights: W2Tb[g][n][k] = bf16(s2[k] * Wg2[k][n]) ----------------
__global__ void k_wt2(const float* __restrict__ s2,
                      const float* __restrict__ W1, const float* __restrict__ W2,
                      const float* __restrict__ W3, unsigned short* __restrict__ W2Tb) {
    const int g = blockIdx.y;
    const float* W = (g == 0) ? W1 : (g == 1) ? W2 : W3;
    const int id = blockIdx.x * 256 + threadIdx.x;   // 0..8191
    const int n = id >> 7, k = id & 127;
    W2Tb[(size_t)g * 8192 + (size_t)n * 128 + k] = f2bf(s2[k] * W[(size_t)k * ODIM + n]);
}

// ================= CSR build via bucket binning (single-writer nbr lines) =================
__global__ __launch_bounds__(256) void k_bincount(
    const int* __restrict__ d0, const int* __restrict__ d1, const int* __restrict__ d2,
    int e0, int e1, int e2, unsigned* __restrict__ cnts) {
    const int g = blockIdx.y, blk = blockIdx.x, t = threadIdx.x;
    const int* dst = (g == 0) ? d0 : (g == 1) ? d1 : d2;
    const int E = (g == 0) ? e0 : (g == 1) ? e1 : e2;
    __shared__ unsigned hist[NBK];
    hist[t] = 0;
    __syncthreads();
    const int chunk = (E + BINB - 1) / BINB;
    const int i0 = blk * chunk, i1 = min(E, i0 + chunk);
    for (int i = i0 + t; i < i1; i += 256) atomicAdd(&hist[((unsigned)dst[i]) >> 8], 1u);
    __syncthreads();
    cnts[((size_t)(g * NBK + t)) * BINB + blk] = hist[t];
}

__global__ __launch_bounds__(256) void k_sa(const unsigned* __restrict__ cnts,
                                            unsigned* __restrict__ bs) {
    const int blk = blockIdx.x, t = threadIdx.x;
    unsigned s = cnts[(size_t)blk * 512 + t] + cnts[(size_t)blk * 512 + 256 + t];
    __shared__ unsigned red[256];
    red[t] = s;
    __syncthreads();
    for (int o = 128; o; o >>= 1) {
        if (t < o) red[t] += red[t + o];
        __syncthreads();
    }
    if (t == 0) bs[blk] = red[0];
}

__global__ void k_sb(unsigned* __restrict__ bs, int n) {
    const int t = threadIdx.x;
    __shared__ unsigned ps[1024];
    unsigned v = (t < n) ? bs[t] : 0u;
    ps[t] = v;
    __syncthreads();
    for (int o = 1; o < 1024; o <<= 1) {
        const unsigned a = (t >= o) ? ps[t - o] : 0u;
        __syncthreads();
        ps[t] += a;
        __syncthreads();
    }
    if (t < n) bs[t] = ps[t] - v;
}

__global__ __launch_bounds__(256) void k_sc(unsigned* __restrict__ cnts,
                                            const unsigned* __restrict__ bs) {
    const int blk = blockIdx.x, t = threadIdx.x;
    const size_t base = (size_t)blk * 512;
    const unsigned e0v = cnts[base + 2 * t];
    const unsigned e1v = cnts[base + 2 * t + 1];
    const unsigned pair = e0v + e1v;
    __shared__ unsigned ps[256];
    ps[t] = pair;
    __syncthreads();
    for (int o = 1; o < 256; o <<= 1) {
        const unsigned a = (t >= o) ? ps[t - o] : 0u;
        __syncthreads();
        ps[t] += a;
        __syncthreads();
    }
    const unsigned ex = ps[t] - pair + bs[blk];
    cnts[base + 2 * t]     = ex;
    cnts[base + 2 * t + 1] = ex + e0v;
}

__global__ __launch_bounds__(256) void k_binplace(
    const int* __restrict__ s0, const int* __restrict__ d0,
    const int* __restrict__ s1, const int* __restrict__ d1,
    const int* __restrict__ s2, const int* __restrict__ d2,
    int e0, int e1, int e2, const unsigned* __restrict__ pos, int2* __restrict__ ebuf) {
    const int g = blockIdx.y, blk = blockIdx.x, t = threadIdx.x;
    const int* src = (g == 0) ? s0 : (g == 1) ? s1 : s2;
    const int* dst = (g == 0) ? d0 : (g == 1) ? d1 : d2;
    const int E = (g == 0) ? e0 : (g == 1) ? e1 : e2;
    __shared__ unsigned cur[NBK];
    cur[t] = pos[((size_t)(g * NBK + t)) * BINB + blk];
    __syncthreads();
    const int chunk = (E + BINB - 1) / BINB;
    const int i0 = blk * chunk, i1 = min(E, i0 + chunk);
    for (int i = i0 + t; i < i1; i += 256) {
        const int dv = dst[i];
        const unsigned p = atomicAdd(&cur[((unsigned)dv) >> 8], 1u);
        ebuf[p] = make_int2(src[i], dv);
    }
}

__global__ __launch_bounds__(256) void k_build(
    const int2* __restrict__ ebuf, const unsigned* __restrict__ pos,
    int etot, int e0, int e1,
    int* __restrict__ off, int* __restrict__ cend, float* __restrict__ rinv,
    int* __restrict__ n0, int* __restrict__ n1, int* __restrict__ n2, int N) {
    const int g = blockIdx.y, b = blockIdx.x, t = threadIdx.x;
    const int v0 = b << 8;
    const int gbase = (g == 0) ? 0 : ((g == 1) ? e0 : e0 + e1);
    int* nbr = (g == 0) ? n0 : ((g == 1) ? n1 : n2);
    const int cell = g * NBK + b;
    const unsigned seg0 = pos[(size_t)cell * BINB];
    const unsigned seg1 = (cell + 1 < 3 * NBK) ? pos[(size_t)(cell + 1) * BINB] : (unsigned)etot;

    __shared__ unsigned deg[NBK];
    __shared__ unsigned ps[NBK];
    __shared__ unsigned cur[NBK];
    deg[t] = 0;
    __syncthreads();
    for (unsigned i = seg0 + t; i < seg1; i += 256) atomicAdd(&deg[ebuf[i].y - v0], 1u);
    __syncthreads();
    const unsigned dv = deg[t];
    ps[t] = dv;
    __syncthreads();
    for (int o = 1; o < 256; o <<= 1) {
        const unsigned a = (t >= o) ? ps[t - o] : 0u;
        __syncthreads();
        ps[t] += a;
        __syncthreads();
    }
    const unsigned ex = ps[t] - dv;     // exclusive within bucket
    const int nbase = (int)seg0 - gbase;
    const int node = v0 + t;
    if (node < N) {
        off[(size_t)g * N + node]  = nbase + (int)ex;
        cend[(size_t)g * N + node] = nbase + (int)(ex + dv);
        rinv[(size_t)g * N + node] = 1.0f / ((float)dv + 1.0f);
    }
    cur[t] = ex;
    __syncthreads();
    for (unsigned i = seg0 + t; i < seg1; i += 256) {
        const int2 e = ebuf[i];
        const unsigned p = atomicAdd(&cur[e.y - v0], 1u);
        nbr[nbase + (int)p] = e.x;
    }
}

// ---------------- gather (bf16 x rows, 3 graphs via blockIdx.y), BN1 fused, bf16 out ----------------
__global__ __launch_bounds__(256) void k_gather3(
    const unsigned short* __restrict__ XB,
    const int* __restrict__ nbr0, const int* __restrict__ nbr1, const int* __restrict__ nbr2,
    const int* __restrict__ off, const int* __restrict__ cend,
    const float* __restrict__ rinv, const float* __restrict__ s1,
    const float* __restrict__ sh1, unsigned short* __restrict__ AGG3b, int N) {
    const int g = blockIdx.y;
    const int* nbr = (g == 0) ? nbr0 : (g == 1) ? nbr1 : nbr2;
    const int gb = g * N;
    const int wave = threadIdx.x >> 6;
    const int lane = threadIdx.x & 63;
    const int v = blockIdx.x * 4 + wave;
    if (v >= N) return;
    const int i0 = off[gb + v], i1 = cend[gb + v];
    const int l2 = lane * 2;
    unsigned sv = ((const unsigned*)(XB + (size_t)v * FDIM))[lane];
    float2 acc;
    acc.x = blo(sv);
    acc.y = bhi(sv);
    int i = i0;
    for (; i + 8 <= i1; i += 8) {
        const int u0 = nbr[i],     u1 = nbr[i + 1], u2 = nbr[i + 2], u3 = nbr[i + 3];
        const int u4 = nbr[i + 4], u5 = nbr[i + 5], u6 = nbr[i + 6], u7 = nbr[i + 7];
        const unsigned a0 = ((const unsigned*)(XB + (size_t)u0 * FDIM))[lane];
        const unsigned a1 = ((const unsigned*)(XB + (size_t)u1 * FDIM))[lane];
        const unsigned a2 = ((const unsigned*)(XB + (size_t)u2 * FDIM))[lane];
        const unsigned a3 = ((const unsigned*)(XB + (size_t)u3 * FDIM))[lane];
        const unsigned a4 = ((const unsigned*)(XB + (size_t)u4 * FDIM))[lane];
        const unsigned a5 = ((const unsigned*)(XB + (size_t)u5 * FDIM))[lane];
        const unsigned a6 = ((const unsigned*)(XB + (size_t)u6 * FDIM))[lane];
        const unsigned a7 = ((const unsigned*)(XB + (size_t)u7 * FDIM))[lane];
        acc.x += ((blo(a0) + blo(a1)) + (blo(a2) + blo(a3))) + ((blo(a4) + blo(a5)) + (blo(a6) + blo(a7)));
        acc.y += ((bhi(a0) + bhi(a1)) + (bhi(a2) + bhi(a3))) + ((bhi(a4) + bhi(a5)) + (bhi(a6) + bhi(a7)));
    }
    for (; i < i1; ++i) {
        const unsigned a = ((const unsigned*)(XB + (size_t)nbr[i] * FDIM))[lane];
        acc.x += blo(a);
        acc.y += bhi(a);
    }
    const float r = rinv[gb + v];
    const float2 sc = *(const float2*)&s1[l2];
    const float2 sh = *(const float2*)&sh1[l2];
    const float ox = fmaf(acc.x * r, sc.x, sh.x);
    const float oy = fmaf(acc.y * r, sc.y, sh.y);
    const unsigned w = (unsigned)f2bf(ox) | ((unsigned)f2bf(oy) << 16);
    ((unsigned*)(AGG3b + ((size_t)(gb + v)) * FDIM))[lane] = w;
}

// ---------------- GEMM1 (MFMA bf16): Hb = bf16(relu( [A0|A1|A2] @ [W1;W2;W3] + sum b )) ----------------
__global__ __launch_bounds__(256) void k_gemm1(
    const unsigned short* __restrict__ AGG3b, const unsigned short* __restrict__ WTb,
    const float* __restrict__ b1, const float* __restrict__ b2, const float* __restrict__ b3,
    unsigned short* __restrict__ Hb, int N) {
    constexpr int AST = 40;                 // padded row stride in shorts (80 B, 16B-aligned)
    __shared__ __align__(16) unsigned short As[64 * AST];
    __shared__ __align__(16) unsigned short Bs[128 * AST];
    const int t = threadIdx.x;
    const int w = t >> 6, l = t & 63;
    const int row0 = blockIdx.x * 64;
    const int cl = l & 15;
    const int hi = l >> 4;
    f32x4 acc[8] = {};

    for (int g = 0; g < 3; ++g) {
        const unsigned short* Ag = AGG3b + (size_t)g * N * FDIM;
        const unsigned short* Wg = WTb + (size_t)g * 16384;
        for (int kb = 0; kb < 4; ++kb) {
            const int k0 = kb * 32;
            {
                const int r = t >> 2, h = t & 3;
                const int row = row0 + r;
                uint4 v = make_uint4(0u, 0u, 0u, 0u);
                if (row < N) v = *(const uint4*)(Ag + (size_t)row * FDIM + k0 + h * 8);
                *(uint4*)(As + r * AST + h * 8) = v;
            }
            {
                const int c = t >> 1, p = t & 1;
                const uint4 v0 = *(const uint4*)(Wg + (size_t)c * 128 + k0 + p * 16);
                const uint4 v1 = *(const uint4*)(Wg + (size_t)c * 128 + k0 + p * 16 + 8);
                *(uint4*)(Bs + c * AST + p * 16)     = v0;
                *(uint4*)(Bs + c * AST + p * 16 + 8) = v1;
            }
            __syncthreads();
            const bf16x8 af = *(const bf16x8*)(As + (w * 16 + cl) * AST + hi * 8);
            #pragma unroll
            for (int c = 0; c < 8; ++c) {
                const bf16x8 bf = *(const bf16x8*)(Bs + (c * 16 + cl) * AST + hi * 8);
                acc[c] = __builtin_amdgcn_mfma_f32_16x16x32_bf16(af, bf, acc[c], 0, 0, 0);
            }
            __syncthreads();
        }
    }
    #pragma unroll
    for (int c = 0; c < 8; ++c) {
        const int col = c * 16 + cl;
        const float bb = b1[col] + b2[col] + b3[col];
        #pragma unroll
        for (int r = 0; r < 4; ++r) {
            const int row = row0 + w * 16 + hi * 4 + r;
            if (row < N) Hb[(size_t)row * FDIM + col] = f2bf(fmaxf(acc[c][r] + bb, 0.f));
        }
    }
}

// ---------------- c2[g][n] = sum_k sh2[k] * Wg[k][n] ----------------
__global__ void k_c2(const float* __restrict__ sh2,
                     const float* __restrict__ W1, const float* __restrict__ W2,
                     const float* __restrict__ W3, float* __restrict__ c2) {
    const int t = threadIdx.x;   // 192
    const int g = t >> 6, n = t & 63;
    const float* W = (g == 0) ? W1 : (g == 1) ? W2 : W3;
    float s = 0.f;
    for (int k = 0; k < 128; ++k) s = fmaf(sh2[k], W[(size_t)k * ODIM + n], s);
    c2[g * ODIM + n] = s;
}

// ---------------- GEMM2 (MFMA bf16): Ub_g = bf16( Hb @ W2Tb_g + c2_g ), 64x64 tile ----------------
__global__ __launch_bounds__(256) void k_gemm2(
    const unsigned short* __restrict__ Hb, const unsigned short* __restrict__ W2Tb,
    const float* __restrict__ c2, unsigned short* __restrict__ Ub, int N) {
    constexpr int AST = 40;
    __shared__ __align__(16) unsigned short As[64 * AST];
    __shared__ __align__(16) unsigned short Bs[64 * AST];
    const int t = threadIdx.x;
    const int g = blockIdx.y;
    const int w = t >> 6, l = t & 63;
    const int row0 = blockIdx.x * 64;
    const int cl = l & 15;
    const int hi = l >> 4;
    const unsigned short* Wg = W2Tb + (size_t)g * 8192;
    f32x4 acc[4] = {};

    for (int kb = 0; kb < 4; ++kb) {
        const int k0 = kb * 32;
        {
            const int r = t >> 2, h = t & 3;
            const int row = row0 + r;
            uint4 v = make_uint4(0u, 0u, 0u, 0u);
            if (row < N) v = *(const uint4*)(Hb + (size_t)row * FDIM + k0 + h * 8);
            *(uint4*)(As + r * AST + h * 8) = v;
        }
        {
            const int c = t >> 2, h = t & 3;
            const uint4 v = *(const uint4*)(Wg + (size_t)c * 128 + k0 + h * 8);
            *(uint4*)(Bs + c * AST + h * 8) = v;
        }
        __syncthreads();
        const bf16x8 af = *(const bf16x8*)(As + (w * 16 + cl) * AST + hi * 8);
        #pragma unroll
        for (int c = 0; c < 4; ++c) {
            const bf16x8 bf = *(const bf16x8*)(Bs + (c * 16 + cl) * AST + hi * 8);
            acc[c] = __builtin_amdgcn_mfma_f32_16x16x32_bf16(af, bf, acc[c], 0, 0, 0);
        }
        __syncthreads();
    }
    const float* cg = c2 + (size_t)g * ODIM;
    unsigned short* Ug = Ub + (size_t)g * N * ODIM;
    #pragma unroll
    for (int c = 0; c < 4; ++c) {
        const int col = c * 16 + cl;
        const float bb = cg[col];
        #pragma unroll
        for (int r = 0; r < 4; ++r) {
            const int row = row0 + w * 16 + hi * 4 + r;
            if (row < N) Ug[(size_t)row * ODIM + col] = f2bf(acc[c][r] + bb);
        }
    }
}

// ---------------- layer-2 gather + combine (bf16 U rows) ----------------
__global__ __launch_bounds__(256) void k_gc64(
    const unsigned short* __restrict__ Ub,
    const int* __restrict__ nbr0, const int* __restrict__ nbr1, const int* __restrict__ nbr2,
    const int* __restrict__ off, const int* __restrict__ cend,
    const float* __restrict__ rinv,
    const float* __restrict__ b1, const float* __restrict__ b2, const float* __restrict__ b3,
    float* __restrict__ Z, int N) {
    const int wave = threadIdx.x >> 6;
    const int lane = threadIdx.x & 63;
    const int v = blockIdx.x * 4 + wave;
    if (v >= N) return;
    const size_t gs = (size_t)N * ODIM;
    float z = b1[lane] + b2[lane] + b3[lane];
    #pragma unroll
    for (int g = 0; g < 3; ++g) {
        const unsigned short* Ug = Ub + (size_t)g * gs;
        const int* nb = (g == 0) ? nbr0 : (g == 1) ? nbr1 : nbr2;
        const int i0 = off[g * N + v], i1 = cend[g * N + v];
        float s = bf2f(Ug[(size_t)v * ODIM + lane]);
        int i = i0;
        for (; i + 8 <= i1; i += 8) {
            const int u0 = nb[i],     u1 = nb[i + 1], u2 = nb[i + 2], u3 = nb[i + 3];
            const int u4 = nb[i + 4], u5 = nb[i + 5], u6 = nb[i + 6], u7 = nb[i + 7];
            const float a0 = bf2f(Ug[(size_t)u0 * ODIM + lane]);
            const float a1 = bf2f(Ug[(size_t)u1 * ODIM + lane]);
            const float a2 = bf2f(Ug[(size_t)u2 * ODIM + lane]);
            const float a3 = bf2f(Ug[(size_t)u3 * ODIM + lane]);
            const float a4 = bf2f(Ug[(size_t)u4 * ODIM + lane]);
            const float a5 = bf2f(Ug[(size_t)u5 * ODIM + lane]);
            const float a6 = bf2f(Ug[(size_t)u6 * ODIM + lane]);
            const float a7 = bf2f(Ug[(size_t)u7 * ODIM + lane]);
            s += ((a0 + a1) + (a2 + a3)) + ((a4 + a5) + (a6 + a7));
        }
        for (; i < i1; ++i) s += bf2f(Ug[(size_t)nb[i] * ODIM + lane]);
        z += s * rinv[g * N + v];
    }
    Z[(size_t)v * ODIM + lane] = z;
}

// ---------------- final: BN3 + sigmoid + row min-max + row L2, in place ----------------
__global__ __launch_bounds__(256) void k_final(float* __restrict__ Z,
                                               const float* __restrict__ scale,
                                               const float* __restrict__ shift, int N) {
    const int wave = threadIdx.x >> 6;
    const int lane = threadIdx.x & 63;
    const int row = blockIdx.x * 4 + wave;
    if (row >= N) return;
    float v = fmaf(Z[(size_t)row * ODIM + lane], scale[lane], shift[lane]);
    float s = 1.0f / (1.0f + expf(-v));
    float mn = s, mx = s;
    #pragma unroll
    for (int off = 32; off; off >>= 1) {
        mn = fminf(mn, __shfl_xor(mn, off, 64));
        mx = fmaxf(mx, __shfl_xor(mx, off, 64));
    }
    const float sc = (s - mn) / (mx - mn);
    float sq = sc * sc;
    #pragma unroll
    for (int off = 32; off; off >>= 1) sq += __shfl_xor(sq, off, 64);
    const float norm = fmaxf(sqrtf(sq), 1e-12f);
    Z[(size_t)row * ODIM + lane] = sc / norm;
}

extern "C" void kernel_launch(void* const* d_in, const int* in_sizes, int n_in,
                              void* d_out, int out_size, void* d_ws, size_t ws_size,
                              hipStream_t stream) {
    const float* x = (const float*)d_in[0];
    const int* src[3] = {(const int*)d_in[1], (const int*)d_in[3], (const int*)d_in[5]};
    const int* dst[3] = {(const int*)d_in[2], (const int*)d_in[4], (const int*)d_in[6]};
    const int E[3] = {in_sizes[1], in_sizes[3], in_sizes[5]};
    const int Etot = E[0] + E[1] + E[2];
    const float* W11 = (const float*)d_in[7];  const float* b11 = (const float*)d_in[8];
    const float* W21 = (const float*)d_in[9];  const float* b21 = (const float*)d_in[10];
    const float* W31 = (const float*)d_in[11]; const float* b31 = (const float*)d_in[12];
    const float* W12 = (const float*)d_in[13]; const float* b12 = (const float*)d_in[14];
    const float* W22 = (const float*)d_in[15]; const float* b22 = (const float*)d_in[16];
    const float* W32 = (const float*)d_in[17]; const float* b32 = (const float*)d_in[18];
    const float* g1  = (const float*)d_in[19]; const float* be1 = (const float*)d_in[20];
    const float* g2  = (const float*)d_in[21]; const float* be2 = (const float*)d_in[22];
    const float* g3  = (const float*)d_in[23]; const float* be3 = (const float*)d_in[24];
    const int N = in_sizes[0] / FDIM;
    float* Z = (float*)d_out;

    // ---- workspace layout ----
    float* ws   = (float*)d_ws;
    float* Hreg = ws;                          // N*128 f32-sized region
    unsigned short* xb = (unsigned short*)Hreg;   // bf16 N*128 (phase 1)
    unsigned short* Hb = (unsigned short*)Hreg;   // bf16 N*128 (phase 2, after xb dead)
    float* REG  = Hreg + (size_t)N * FDIM;     // 3*N*128 f32-sized region
    unsigned short* AGG3b = (unsigned short*)REG;   // bf16 3*N*128
    unsigned short* Ub = (unsigned short*)REG;      // bf16 3*N*64 (after AGG3b dead)
    int2* ebuf = (int2*)REG;                                   // Etot int2 (pre-gather)
    unsigned* cnts = (unsigned*)(ebuf + (size_t)Etot);         // 3*NBK*BINB
    unsigned* bs   = cnts + (size_t)3 * NBK * BINB;            // 768
    float* rinv = REG + (size_t)3 * N * FDIM;  // 3N
    float* partial = rinv + (size_t)3 * N;     // CSB*256 = 131072
    float* s1  = partial + (size_t)CSB * 256;  float* sh1 = s1 + 128;
    float* s2  = sh1 + 128;        float* sh2 = s2 + 128;
    float* s3  = sh2 + 128;        float* sh3 = s3 + 64;
    float* c2  = sh3 + 64;                     // 3*64
    unsigned short* WTb  = (unsigned short*)(c2 + 3 * ODIM);  // bf16 3*128*128
    unsigned short* W2Tb = WTb + (size_t)3 * 16384;           // bf16 3*64*128
    int* off  = (int*)(W2Tb + (size_t)3 * 8192);          // 3N
    int* cend = off + (size_t)3 * N;                      // 3N
    int* nbr  = cend + (size_t)3 * N;                     // Etot
    int* nbrg[3];
    nbrg[0] = nbr;
    nbrg[1] = nbrg[0] + E[0];
    nbrg[2] = nbrg[1] + E[1];

    // ---- CSR build via bucket binning (single-writer nbr lines) ----
    const int nbuckets = (N + 255) >> 8;
    k_bincount<<<dim3(BINB, 3), 256, 0, stream>>>(dst[0], dst[1], dst[2],
                                                  E[0], E[1], E[2], cnts);
    k_sa<<<3 * NBK * BINB / 512, 256, 0, stream>>>(cnts, bs);
    k_sb<<<1, 1024, 0, stream>>>(bs, 3 * NBK * BINB / 512);
    k_sc<<<3 * NBK * BINB / 512, 256, 0, stream>>>(cnts, bs);
    k_binplace<<<dim3(BINB, 3), 256, 0, stream>>>(src[0], dst[0], src[1], dst[1],
                                                  src[2], dst[2], E[0], E[1], E[2],
                                                  cnts, ebuf);
    k_build<<<dim3(nbuckets, 3), 256, 0, stream>>>(ebuf, cnts, Etot, E[0], E[1],
                                                   off, cend, rinv,
                                                   nbrg[0], nbrg[1], nbrg[2], N);

    // ---- BN1 stats + fused bf16 conversion of x; bf16 transposed layer-1 weights ----
    k_cs128<<<CSB, 256, 0, stream>>>(x, N, partial, xb);
    k_fin<128><<<128, 256, 0, stream>>>(partial, CSB, N, g1, be1, s1, sh1);
    k_wt<<<dim3(64, 3), 256, 0, stream>>>(W11, W21, W31, WTb);

    // ---- layer 1: 3-graph bf16 gather (bf16 out) -> MFMA K=384 GEMM -> Hb ----
    const int gblocks = (N + 3) / 4;
    k_gather3<<<dim3(gblocks, 3), 256, 0, stream>>>(xb, nbrg[0], nbrg[1], nbrg[2],
                                                    off, cend, rinv, s1, sh1, AGG3b, N);
    k_gemm1<<<(N + 63) / 64, 256, 0, stream>>>(AGG3b, WTb, b11, b21, b31, Hb, N);

    // ---- BN2 stats (from bf16 Hb); scale folded into W2Tb, shift via c2 ----
    k_cs128b<<<CSB, 256, 0, stream>>>(Hb, N, partial);
    k_fin<128><<<128, 256, 0, stream>>>(partial, CSB, N, g2, be2, s2, sh2);
    k_c2<<<1, 192, 0, stream>>>(sh2, W12, W22, W32, c2);
    k_wt2<<<dim3(32, 3), 256, 0, stream>>>(s2, W12, W22, W32, W2Tb);

    // ---- layer 2: MFMA GEMM (bf16 Ub over dead AGG3b), then bf16 gather+combine ----
    dim3 grid2((N + 63) / 64, 3);
    k_gemm2<<<grid2, 256, 0, stream>>>(Hb, W2Tb, c2, Ub, N);
    k_gc64<<<gblocks, 256, 0, stream>>>(Ub, nbrg[0], nbrg[1], nbrg[2], off, cend, rinv,
                                        b12, b22, b32, Z, N);

    // ---- BN3 + epilogue ----
    k_cs64<<<CSB, 256, 0, stream>>>(Z, N, partial);
    k_fin<64><<<64, 256, 0, stream>>>(partial, CSB, N, g3, be3, s3, sh3);
    k_final<<<(N + 3) / 4, 256, 0, stream>>>(Z, s3, sh3, N);
}

// Round 14
// 352.397 us; speedup vs baseline: 2.0748x; 1.0785x over previous
//
#include <hip/hip_runtime.h>
#include <math.h>

constexpr int FDIM = 128;   // IN == HID
constexpr int ODIM = 64;    // NC
constexpr int BINB = 512;   // binning blocks per graph
constexpr int NBK  = 256;   // max buckets (256 nodes each -> N <= 65536; also src packs in 16 bits)
constexpr int CSB  = 512;   // colstats blocks

typedef short bf16x8 __attribute__((ext_vector_type(8)));   // 8 bf16 in 4 VGPRs
typedef float f32x4  __attribute__((ext_vector_type(4)));

// bf16 helpers (RNE pack, bit-shift unpack)
__device__ inline unsigned short f2bf(float f) {
    unsigned u = __float_as_uint(f);
    u = (u + 0x7fffu + ((u >> 16) & 1u)) >> 16;
    return (unsigned short)u;
}
__device__ inline float bf2f(unsigned short s) { return __uint_as_float(((unsigned)s) << 16); }
__device__ inline float blo(unsigned v) { return __uint_as_float(v << 16); }
__device__ inline float bhi(unsigned v) { return __uint_as_float(v & 0xffff0000u); }

// ---------------- column stats, C=128 (f32 in, bf16 emit), CSB x 256 ----------------
__global__ __launch_bounds__(256) void k_cs128(const float* __restrict__ X, int N,
                                               float* __restrict__ partial,
                                               unsigned short* __restrict__ XB) {
    const int t = threadIdx.x;
    const int rh = t >> 7, c = t & 127;
    const int rows_per = (N + gridDim.x - 1) / gridDim.x;
    const int r0 = blockIdx.x * rows_per;
    const int r1 = min(N, r0 + rows_per);
    float s = 0.f, ss = 0.f;
    for (int r = r0 + rh; r < r1; r += 2) {
        const float v = X[(size_t)r * 128 + c];
        s += v;
        ss += v * v;
        XB[(size_t)r * 128 + c] = f2bf(v);
    }
    __shared__ float shs[256], shss[256];
    shs[t] = s;
    shss[t] = ss;
    __syncthreads();
    if (rh == 0) {
        partial[(size_t)blockIdx.x * 256 + c]       = s + shs[t + 128];
        partial[(size_t)blockIdx.x * 256 + 128 + c] = ss + shss[t + 128];
    }
}

// C=64 f32 variant (for Z)
__global__ __launch_bounds__(256) void k_cs64(const float* __restrict__ X, int N,
                                              float* __restrict__ partial) {
    const int t = threadIdx.x;
    const int rh = t >> 6, c = t & 63;       // 4 rows x 64 cols
    const int rows_per = (N + gridDim.x - 1) / gridDim.x;
    const int r0 = blockIdx.x * rows_per;
    const int r1 = min(N, r0 + rows_per);
    float s = 0.f, ss = 0.f;
    for (int r = r0 + rh; r < r1; r += 4) {
        const float v = X[(size_t)r * 64 + c];
        s += v;
        ss += v * v;
    }
    __shared__ float shs[256], shss[256];
    shs[t] = s;
    shss[t] = ss;
    __syncthreads();
    if (rh == 0) {
        partial[(size_t)blockIdx.x * 128 + c] =
            s + shs[t + 64] + shs[t + 128] + shs[t + 192];
        partial[(size_t)blockIdx.x * 128 + 64 + c] =
            ss + shss[t + 64] + shss[t + 128] + shss[t + 192];
    }
}

// ---------------- parallel stats finalize: one block per channel ----------------
template<int C>
__global__ __launch_bounds__(256) void k_fin(const float* __restrict__ partial, int nb, int N,
                                             const float* __restrict__ gamma,
                                             const float* __restrict__ beta,
                                             float* __restrict__ scale,
                                             float* __restrict__ shift) {
    const int c = blockIdx.x;       // 0..C-1
    const int t = threadIdx.x;      // 256
    float s = 0.f, ss = 0.f;
    for (int b = t; b < nb; b += 256) {
        s  += partial[(size_t)b * (2 * C) + c];
        ss += partial[(size_t)b * (2 * C) + C + c];
    }
    __shared__ float shs[256], shss[256];
    shs[t] = s;
    shss[t] = ss;
    __syncthreads();
    for (int o = 128; o; o >>= 1) {
        if (t < o) { shs[t] += shs[t + o]; shss[t] += shss[t + o]; }
        __syncthreads();
    }
    if (t == 0) {
        const float mu  = shs[0] / (float)N;
        const float var = shss[0] / (float)N - mu * mu;
        const float sc  = gamma[c] * rsqrtf(var + 1e-5f);
        scale[c] = sc;
        shift[c] = beta[c] - mu * sc;
    }
}

// ---------------- weights -> bf16 transposed: WTb[g][n][k] = bf16(Wg[k][n]) (layer1) ----------------
__global__ void k_wt(const float* __restrict__ W1, const float* __restrict__ W2,
                     const float* __restrict__ W3, unsigned short* __restrict__ WTb) {
    const int g = blockIdx.y;
    const float* W = (g == 0) ? W1 : (g == 1) ? W2 : W3;
    const int id = blockIdx.x * 256 + threadIdx.x;   // 0..16383
    const int n = id >> 7, k = id & 127;
    WTb[(size_t)g * 16384 + (size_t)n * 128 + k] = f2bf(W[(size_t)k * 128 + n]);
}

// ---------------- layer2 weights: W2Tb[g][n][k] = bf16(s2[k] * Wg2[k][n]) ----------------
__global__ void k_wt2(const float* __restrict__ s2,
                      const float* __restrict__ W1, const float* __restrict__ W2,
                      const float* __restrict__ W3, unsigned short* __restrict__ W2Tb) {
    const int g = blockIdx.y;
    const float* W = (g == 0) ? W1 : (g == 1) ? W2 : W3;
    const int id = blockIdx.x * 256 + threadIdx.x;   // 0..8191
    const int n = id >> 7, k = id & 127;
    W2Tb[(size_t)g * 8192 + (size_t)n * 128 + k] = f2bf(s2[k] * W[(size_t)k * ODIM + n]);
}

// ---------------- c2[g][n] = sum_k sh2[k] * Wg[k][n], parallel (3 blocks x 256) ----------------
__global__ __launch_bounds__(256) void k_c2(const float* __restrict__ sh2,
                                            const float* __restrict__ W1,
                                            const float* __restrict__ W2,
                                            const float* __restrict__ W3,
                                            float* __restrict__ c2) {
    const int g = blockIdx.x;
    const int t = threadIdx.x;
    const int n = t & 63, kq = t >> 6;    // 4 k-quarters of 32
    const float* W = (g == 0) ? W1 : (g == 1) ? W2 : W3;
    float s = 0.f;
    for (int k = kq * 32; k < kq * 32 + 32; ++k)
        s = fmaf(sh2[k], W[(size_t)k * ODIM + n], s);
    __shared__ float red[256];
    red[t] = s;
    __syncthreads();
    if (kq == 0) c2[g * ODIM + n] = red[n] + red[64 + n] + red[128 + n] + red[192 + n];
}

// ================= CSR build via bucket binning (single-writer nbr lines) =================
__global__ __launch_bounds__(256) void k_bincount(
    const int* __restrict__ d0, const int* __restrict__ d1, const int* __restrict__ d2,
    int e0, int e1, int e2, unsigned* __restrict__ cnts) {
    const int g = blockIdx.y, blk = blockIdx.x, t = threadIdx.x;
    const int* dst = (g == 0) ? d0 : (g == 1) ? d1 : d2;
    const int E = (g == 0) ? e0 : (g == 1) ? e1 : e2;
    __shared__ unsigned hist[NBK];
    hist[t] = 0;
    __syncthreads();
    const int chunk = (E + BINB - 1) / BINB;
    const int i0 = blk * chunk, i1 = min(E, i0 + chunk);
    for (int i = i0 + t; i < i1; i += 256) atomicAdd(&hist[((unsigned)dst[i]) >> 8], 1u);
    __syncthreads();
    cnts[((size_t)(g * NBK + t)) * BINB + blk] = hist[t];
}

__global__ __launch_bounds__(256) void k_sa(const unsigned* __restrict__ cnts,
                                            unsigned* __restrict__ bs) {
    const int blk = blockIdx.x, t = threadIdx.x;
    unsigned s = cnts[(size_t)blk * 512 + t] + cnts[(size_t)blk * 512 + 256 + t];
    __shared__ unsigned red[256];
    red[t] = s;
    __syncthreads();
    for (int o = 128; o; o >>= 1) {
        if (t < o) red[t] += red[t + o];
        __syncthreads();
    }
    if (t == 0) bs[blk] = red[0];
}

__global__ void k_sb(unsigned* __restrict__ bs, int n) {
    const int t = threadIdx.x;
    __shared__ unsigned ps[1024];
    unsigned v = (t < n) ? bs[t] : 0u;
    ps[t] = v;
    __syncthreads();
    for (int o = 1; o < 1024; o <<= 1) {
        const unsigned a = (t >= o) ? ps[t - o] : 0u;
        __syncthreads();
        ps[t] += a;
        __syncthreads();
    }
    if (t < n) bs[t] = ps[t] - v;
}

__global__ __launch_bounds__(256) void k_sc(unsigned* __restrict__ cnts,
                                            const unsigned* __restrict__ bs) {
    const int blk = blockIdx.x, t = threadIdx.x;
    const size_t base = (size_t)blk * 512;
    const unsigned e0v = cnts[base + 2 * t];
    const unsigned e1v = cnts[base + 2 * t + 1];
    const unsigned pair = e0v + e1v;
    __shared__ unsigned ps[256];
    ps[t] = pair;
    __syncthreads();
    for (int o = 1; o < 256; o <<= 1) {
        const unsigned a = (t >= o) ? ps[t - o] : 0u;
        __syncthreads();
        ps[t] += a;
        __syncthreads();
    }
    const unsigned ex = ps[t] - pair + bs[blk];
    cnts[base + 2 * t]     = ex;
    cnts[base + 2 * t + 1] = ex + e0v;
}

// packed edge record: src in bits 0..15 (requires N <= 65536), dst&255 in bits 16..23
__global__ __launch_bounds__(256) void k_binplace(
    const int* __restrict__ s0, const int* __restrict__ d0,
    const int* __restrict__ s1, const int* __restrict__ d1,
    const int* __restrict__ s2, const int* __restrict__ d2,
    int e0, int e1, int e2, const unsigned* __restrict__ pos, unsigned* __restrict__ ebuf) {
    const int g = blockIdx.y, blk = blockIdx.x, t = threadIdx.x;
    const int* src = (g == 0) ? s0 : (g == 1) ? s1 : s2;
    const int* dst = (g == 0) ? d0 : (g == 1) ? d1 : d2;
    const int E = (g == 0) ? e0 : (g == 1) ? e1 : e2;
    __shared__ unsigned cur[NBK];
    cur[t] = pos[((size_t)(g * NBK + t)) * BINB + blk];
    __syncthreads();
    const int chunk = (E + BINB - 1) / BINB;
    const int i0 = blk * chunk, i1 = min(E, i0 + chunk);
    for (int i = i0 + t; i < i1; i += 256) {
        const unsigned dv = (unsigned)dst[i];
        const unsigned p = atomicAdd(&cur[dv >> 8], 1u);
        ebuf[p] = (unsigned)src[i] | ((dv & 255u) << 16);
    }
}

__global__ __launch_bounds__(256) void k_build(
    const unsigned* __restrict__ ebuf, const unsigned* __restrict__ pos,
    int etot, int e0, int e1,
    int* __restrict__ off, int* __restrict__ cend, float* __restrict__ rinv,
    int* __restrict__ n0, int* __restrict__ n1, int* __restrict__ n2, int N) {
    const int g = blockIdx.y, b = blockIdx.x, t = threadIdx.x;
    const int v0 = b << 8;
    const int gbase = (g == 0) ? 0 : ((g == 1) ? e0 : e0 + e1);
    int* nbr = (g == 0) ? n0 : ((g == 1) ? n1 : n2);
    const int cell = g * NBK + b;
    const unsigned seg0 = pos[(size_t)cell * BINB];
    const unsigned seg1 = (cell + 1 < 3 * NBK) ? pos[(size_t)(cell + 1) * BINB] : (unsigned)etot;

    __shared__ unsigned deg[NBK];
    __shared__ unsigned ps[NBK];
    __shared__ unsigned cur[NBK];
    deg[t] = 0;
    __syncthreads();
    for (unsigned i = seg0 + t; i < seg1; i += 256)
        atomicAdd(&deg[(ebuf[i] >> 16) & 255u], 1u);
    __syncthreads();
    const unsigned dv = deg[t];
    ps[t] = dv;
    __syncthreads();
    for (int o = 1; o < 256; o <<= 1) {
        const unsigned a = (t >= o) ? ps[t - o] : 0u;
        __syncthreads();
        ps[t] += a;
        __syncthreads();
    }
    const unsigned ex = ps[t] - dv;     // exclusive within bucket
    const int nbase = (int)seg0 - gbase;
    const int node = v0 + t;
    if (node < N) {
        off[(size_t)g * N + node]  = nbase + (int)ex;
        cend[(size_t)g * N + node] = nbase + (int)(ex + dv);
        rinv[(size_t)g * N + node] = 1.0f / ((float)dv + 1.0f);
    }
    cur[t] = ex;
    __syncthreads();
    for (unsigned i = seg0 + t; i < seg1; i += 256) {
        const unsigned e = ebuf[i];
        const unsigned p = atomicAdd(&cur[(e >> 16) & 255u], 1u);
        nbr[nbase + (int)p] = (int)(e & 0xFFFFu);
    }
}

// ---------------- gather (bf16 x rows, 3 graphs via blockIdx.y), BN1 fused, bf16 out ----------------
__global__ __launch_bounds__(256) void k_gather3(
    const unsigned short* __restrict__ XB,
    const int* __restrict__ nbr0, const int* __restrict__ nbr1, const int* __restrict__ nbr2,
    const int* __restrict__ off, const int* __restrict__ cend,
    const float* __restrict__ rinv, const float* __restrict__ s1,
    const float* __restrict__ sh1, unsigned short* __restrict__ AGG3b, int N) {
    const int g = blockIdx.y;
    const int* nbr = (g == 0) ? nbr0 : (g == 1) ? nbr1 : nbr2;
    const int gb = g * N;
    const int wave = threadIdx.x >> 6;
    const int lane = threadIdx.x & 63;
    const int v = blockIdx.x * 4 + wave;
    if (v >= N) return;
    const int i0 = off[gb + v], i1 = cend[gb + v];
    const int l2 = lane * 2;
    unsigned sv = ((const unsigned*)(XB + (size_t)v * FDIM))[lane];
    float2 acc;
    acc.x = blo(sv);
    acc.y = bhi(sv);
    int i = i0;
    for (; i + 8 <= i1; i += 8) {
        const int u0 = nbr[i],     u1 = nbr[i + 1], u2 = nbr[i + 2], u3 = nbr[i + 3];
        const int u4 = nbr[i + 4], u5 = nbr[i + 5], u6 = nbr[i + 6], u7 = nbr[i + 7];
        const unsigned a0 = ((const unsigned*)(XB + (size_t)u0 * FDIM))[lane];
        const unsigned a1 = ((const unsigned*)(XB + (size_t)u1 * FDIM))[lane];
        const unsigned a2 = ((const unsigned*)(XB + (size_t)u2 * FDIM))[lane];
        const unsigned a3 = ((const unsigned*)(XB + (size_t)u3 * FDIM))[lane];
        const unsigned a4 = ((const unsigned*)(XB + (size_t)u4 * FDIM))[lane];
        const unsigned a5 = ((const unsigned*)(XB + (size_t)u5 * FDIM))[lane];
        const unsigned a6 = ((const unsigned*)(XB + (size_t)u6 * FDIM))[lane];
        const unsigned a7 = ((const unsigned*)(XB + (size_t)u7 * FDIM))[lane];
        acc.x += ((blo(a0) + blo(a1)) + (blo(a2) + blo(a3))) + ((blo(a4) + blo(a5)) + (blo(a6) + blo(a7)));
        acc.y += ((bhi(a0) + bhi(a1)) + (bhi(a2) + bhi(a3))) + ((bhi(a4) + bhi(a5)) + (bhi(a6) + bhi(a7)));
    }
    for (; i < i1; ++i) {
        const unsigned a = ((const unsigned*)(XB + (size_t)nbr[i] * FDIM))[lane];
        acc.x += blo(a);
        acc.y += bhi(a);
    }
    const float r = rinv[gb + v];
    const float2 sc = *(const float2*)&s1[l2];
    const float2 sh = *(const float2*)&sh1[l2];
    const float ox = fmaf(acc.x * r, sc.x, sh.x);
    const float oy = fmaf(acc.y * r, sc.y, sh.y);
    const unsigned w = (unsigned)f2bf(ox) | ((unsigned)f2bf(oy) << 16);
    ((unsigned*)(AGG3b + ((size_t)(gb + v)) * FDIM))[lane] = w;
}

// ---------------- GEMM1 (MFMA bf16) + fused BN2 column stats ----------------
// Hb = bf16(relu([A0|A1|A2] @ [W1;W2;W3] + sum b)); partial[blk] = col sums/sumsq of Hb tile
__global__ __launch_bounds__(256) void k_gemm1(
    const unsigned short* __restrict__ AGG3b, const unsigned short* __restrict__ WTb,
    const float* __restrict__ b1, const float* __restrict__ b2, const float* __restrict__ b3,
    unsigned short* __restrict__ Hb, float* __restrict__ partial, int N) {
    constexpr int AST = 40;                 // padded row stride in shorts (80 B, 16B-aligned)
    __shared__ __align__(16) unsigned short As[64 * AST];
    __shared__ __align__(16) unsigned short Bs[128 * AST];
    __shared__ float sst[4][128], ssq[4][128];
    const int t = threadIdx.x;
    const int w = t >> 6, l = t & 63;
    const int row0 = blockIdx.x * 64;
    const int cl = l & 15;
    const int hi = l >> 4;
    f32x4 acc[8] = {};

    for (int g = 0; g < 3; ++g) {
        const unsigned short* Ag = AGG3b + (size_t)g * N * FDIM;
        const unsigned short* Wg = WTb + (size_t)g * 16384;
        for (int kb = 0; kb < 4; ++kb) {
            const int k0 = kb * 32;
            {
                const int r = t >> 2, h = t & 3;
                const int row = row0 + r;
                uint4 v = make_uint4(0u, 0u, 0u, 0u);
                if (row < N) v = *(const uint4*)(Ag + (size_t)row * FDIM + k0 + h * 8);
                *(uint4*)(As + r * AST + h * 8) = v;
            }
            {
                const int c = t >> 1, p = t & 1;
                const uint4 v0 = *(const uint4*)(Wg + (size_t)c * 128 + k0 + p * 16);
                const uint4 v1 = *(const uint4*)(Wg + (size_t)c * 128 + k0 + p * 16 + 8);
                *(uint4*)(Bs + c * AST + p * 16)     = v0;
                *(uint4*)(Bs + c * AST + p * 16 + 8) = v1;
            }
            __syncthreads();
            const bf16x8 af = *(const bf16x8*)(As + (w * 16 + cl) * AST + hi * 8);
            #pragma unroll
            for (int c = 0; c < 8; ++c) {
                const bf16x8 bf = *(const bf16x8*)(Bs + (c * 16 + cl) * AST + hi * 8);
                acc[c] = __builtin_amdgcn_mfma_f32_16x16x32_bf16(af, bf, acc[c], 0, 0, 0);
            }
            __syncthreads();
        }
    }
    float s8[8], q8[8];
    #pragma unroll
    for (int c = 0; c < 8; ++c) {
        const int col = c * 16 + cl;
        const float bb = b1[col] + b2[col] + b3[col];
        float s = 0.f, q = 0.f;
        #pragma unroll
        for (int r = 0; r < 4; ++r) {
            const int row = row0 + w * 16 + hi * 4 + r;
            if (row < N) {
                const unsigned short hb = f2bf(fmaxf(acc[c][r] + bb, 0.f));
                Hb[(size_t)row * FDIM + col] = hb;
                const float h = bf2f(hb);
                s += h;
                q += h * h;
            }
        }
        s8[c] = s;
        q8[c] = q;
    }
    #pragma unroll
    for (int c = 0; c < 8; ++c) {
        s8[c] += __shfl_xor(s8[c], 16, 64); s8[c] += __shfl_xor(s8[c], 32, 64);
        q8[c] += __shfl_xor(q8[c], 16, 64); q8[c] += __shfl_xor(q8[c], 32, 64);
    }
    if (hi == 0) {
        #pragma unroll
        for (int c = 0; c < 8; ++c) {
            sst[w][c * 16 + cl] = s8[c];
            ssq[w][c * 16 + cl] = q8[c];
        }
    }
    __syncthreads();
    if (t < 128) {
        partial[(size_t)blockIdx.x * 256 + t]       = sst[0][t] + sst[1][t] + sst[2][t] + sst[3][t];
        partial[(size_t)blockIdx.x * 256 + 128 + t] = ssq[0][t] + ssq[1][t] + ssq[2][t] + ssq[3][t];
    }
}

// ---------------- GEMM2 (MFMA bf16): Ub_g = bf16( Hb @ W2Tb_g + c2_g ), 64x64 tile ----------------
__global__ __launch_bounds__(256) void k_gemm2(
    const unsigned short* __restrict__ Hb, const unsigned short* __restrict__ W2Tb,
    const float* __restrict__ c2, unsigned short* __restrict__ Ub, int N) {
    constexpr int AST = 40;
    __shared__ __align__(16) unsigned short As[64 * AST];
    __shared__ __align__(16) unsigned short Bs[64 * AST];
    const int t = threadIdx.x;
    const int g = blockIdx.y;
    const int w = t >> 6, l = t & 63;
    const int row0 = blockIdx.x * 64;
    const int cl = l & 15;
    const int hi = l >> 4;
    const unsigned short* Wg = W2Tb + (size_t)g * 8192;
    f32x4 acc[4] = {};

    for (int kb = 0; kb < 4; ++kb) {
        const int k0 = kb * 32;
        {
            const int r = t >> 2, h = t & 3;
            const int row = row0 + r;
            uint4 v = make_uint4(0u, 0u, 0u, 0u);
            if (row < N) v = *(const uint4*)(Hb + (size_t)row * FDIM + k0 + h * 8);
            *(uint4*)(As + r * AST + h * 8) = v;
        }
        {
            const int c = t >> 2, h = t & 3;
            const uint4 v = *(const uint4*)(Wg + (size_t)c * 128 + k0 + h * 8);
            *(uint4*)(Bs + c * AST + h * 8) = v;
        }
        __syncthreads();
        const bf16x8 af = *(const bf16x8*)(As + (w * 16 + cl) * AST + hi * 8);
        #pragma unroll
        for (int c = 0; c < 4; ++c) {
            const bf16x8 bf = *(const bf16x8*)(Bs + (c * 16 + cl) * AST + hi * 8);
            acc[c] = __builtin_amdgcn_mfma_f32_16x16x32_bf16(af, bf, acc[c], 0, 0, 0);
        }
        __syncthreads();
    }
    const float* cg = c2 + (size_t)g * ODIM;
    unsigned short* Ug = Ub + (size_t)g * N * ODIM;
    #pragma unroll
    for (int c = 0; c < 4; ++c) {
        const int col = c * 16 + cl;
        const float bb = cg[col];
        #pragma unroll
        for (int r = 0; r < 4; ++r) {
            const int row = row0 + w * 16 + hi * 4 + r;
            if (row < N) Ug[(size_t)row * ODIM + col] = f2bf(acc[c][r] + bb);
        }
    }
}

// ---------------- layer-2 gather + combine (bf16 U rows) ----------------
__global__ __launch_bounds__(256) void k_gc64(
    const unsigned short* __restrict__ Ub,
    const int* __restrict__ nbr0, const int* __restrict__ nbr1, const int* __restrict__ nbr2,
    const int* __restrict__ off, const int* __restrict__ cend,
    const float* __restrict__ rinv,
    const float* __restrict__ b1, const float* __restrict__ b2, const float* __restrict__ b3,
    float* __restrict__ Z, int N) {
    const int wave = threadIdx.x >> 6;
    const int lane = threadIdx.x & 63;
    const int v = blockIdx.x * 4 + wave;
    if (v >= N) return;
    const size_t gs = (size_t)N * ODIM;
    float z = b1[lane] + b2[lane] + b3[lane];
    #pragma unroll
    for (int g = 0; g < 3; ++g) {
        const unsigned short* Ug = Ub + (size_t)g * gs;
        const int* nb = (g == 0) ? nbr0 : (g == 1) ? nbr1 : nbr2;
        const int i0 = off[g * N + v], i1 = cend[g * N + v];
        float s = bf2f(Ug[(size_t)v * ODIM + lane]);
        int i = i0;
        for (; i + 8 <= i1; i += 8) {
            const int u0 = nb[i],     u1 = nb[i + 1], u2 = nb[i + 2], u3 = nb[i + 3];
            const int u4 = nb[i + 4], u5 = nb[i + 5], u6 = nb[i + 6], u7 = nb[i + 7];
            const float a0 = bf2f(Ug[(size_t)u0 * ODIM + lane]);
            const float a1 = bf2f(Ug[(size_t)u1 * ODIM + lane]);
            const float a2 = bf2f(Ug[(size_t)u2 * ODIM + lane]);
            const float a3 = bf2f(Ug[(size_t)u3 * ODIM + lane]);
            const float a4 = bf2f(Ug[(size_t)u4 * ODIM + lane]);
            const float a5 = bf2f(Ug[(size_t)u5 * ODIM + lane]);
            const float a6 = bf2f(Ug[(size_t)u6 * ODIM + lane]);
            const float a7 = bf2f(Ug[(size_t)u7 * ODIM + lane]);
            s += ((a0 + a1) + (a2 + a3)) + ((a4 + a5) + (a6 + a7));
        }
        for (; i < i1; ++i) s += bf2f(Ug[(size_t)nb[i] * ODIM + lane]);
        z += s * rinv[g * N + v];
    }
    Z[(size_t)v * ODIM + lane] = z;
}

// ---------------- final: BN3 + sigmoid + row min-max + row L2, in place ----------------
__global__ __launch_bounds__(256) void k_final(float* __restrict__ Z,
                                               const float* __restrict__ scale,
                                               const float* __restrict__ shift, int N) {
    const int wave = threadIdx.x >> 6;
    const int lane = threadIdx.x & 63;
    const int row = blockIdx.x * 4 + wave;
    if (row >= N) return;
    float v = fmaf(Z[(size_t)row * ODIM + lane], scale[lane], shift[lane]);
    float s = 1.0f / (1.0f + expf(-v));
    float mn = s, mx = s;
    #pragma unroll
    for (int off = 32; off; off >>= 1) {
        mn = fminf(mn, __shfl_xor(mn, off, 64));
        mx = fmaxf(mx, __shfl_xor(mx, off, 64));
    }
    const float sc = (s - mn) / (mx - mn);
    float sq = sc * sc;
    #pragma unroll
    for (int off = 32; off; off >>= 1) sq += __shfl_xor(sq, off, 64);
    const float norm = fmaxf(sqrtf(sq), 1e-12f);
    Z[(size_t)row * ODIM + lane] = sc / norm;
}

extern "C" void kernel_launch(void* const* d_in, const int* in_sizes, int n_in,
                              void* d_out, int out_size, void* d_ws, size_t ws_size,
                              hipStream_t stream) {
    const float* x = (const float*)d_in[0];
    const int* src[3] = {(const int*)d_in[1], (const int*)d_in[3], (const int*)d_in[5]};
    const int* dst[3] = {(const int*)d_in[2], (const int*)d_in[4], (const int*)d_in[6]};
    const int E[3] = {in_sizes[1], in_sizes[3], in_sizes[5]};
    const int Etot = E[0] + E[1] + E[2];
    const float* W11 = (const float*)d_in[7];  const float* b11 = (const float*)d_in[8];
    const float* W21 = (const float*)d_in[9];  const float* b21 = (const float*)d_in[10];
    const float* W31 = (const float*)d_in[11]; const float* b31 = (const float*)d_in[12];
    const float* W12 = (const float*)d_in[13]; const float* b12 = (const float*)d_in[14];
    const float* W22 = (const float*)d_in[15]; const float* b22 = (const float*)d_in[16];
    const float* W32 = (const float*)d_in[17]; const float* b32 = (const float*)d_in[18];
    const float* g1  = (const float*)d_in[19]; const float* be1 = (const float*)d_in[20];
    const float* g2  = (const float*)d_in[21]; const float* be2 = (const float*)d_in[22];
    const float* g3  = (const float*)d_in[23]; const float* be3 = (const float*)d_in[24];
    const int N = in_sizes[0] / FDIM;
    float* Z = (float*)d_out;
    const int gblocks1 = (N + 63) / 64;        // gemm1 blocks (BN2 stats partials)

    // ---- workspace layout ----
    float* ws   = (float*)d_ws;
    float* Hreg = ws;                          // N*128 f32-sized region
    unsigned short* xb = (unsigned short*)Hreg;   // bf16 N*128 (phase 1)
    unsigned short* Hb = (unsigned short*)Hreg;   // bf16 N*128 (phase 2, after xb dead)
    float* REG  = Hreg + (size_t)N * FDIM;     // 3*N*128 f32-sized region
    unsigned short* AGG3b = (unsigned short*)REG;   // bf16 3*N*128
    unsigned short* Ub = (unsigned short*)REG;      // bf16 3*N*64 (after AGG3b dead)
    unsigned* ebuf = (unsigned*)REG;                           // Etot u32 (pre-gather)
    unsigned* cnts = ebuf + (size_t)Etot;                      // 3*NBK*BINB
    unsigned* bs   = cnts + (size_t)3 * NBK * BINB;            // 768
    float* rinv = REG + (size_t)3 * N * FDIM;  // 3N
    float* partial = rinv + (size_t)3 * N;     // max(CSB*256, gblocks1*256) floats
    const size_t psz = (size_t)((gblocks1 > CSB ? gblocks1 : CSB)) * 256;
    float* s1  = partial + psz;    float* sh1 = s1 + 128;
    float* s2  = sh1 + 128;        float* sh2 = s2 + 128;
    float* s3  = sh2 + 128;        float* sh3 = s3 + 64;
    float* c2  = sh3 + 64;                     // 3*64
    unsigned short* WTb  = (unsigned short*)(c2 + 3 * ODIM);  // bf16 3*128*128
    unsigned short* W2Tb = WTb + (size_t)3 * 16384;           // bf16 3*64*128
    int* off  = (int*)(W2Tb + (size_t)3 * 8192);          // 3N
    int* cend = off + (size_t)3 * N;                      // 3N
    int* nbr  = cend + (size_t)3 * N;                     // Etot
    int* nbrg[3];
    nbrg[0] = nbr;
    nbrg[1] = nbrg[0] + E[0];
    nbrg[2] = nbrg[1] + E[1];

    // ---- CSR build via bucket binning (single-writer nbr lines, packed u32 records) ----
    const int nbuckets = (N + 255) >> 8;
    k_bincount<<<dim3(BINB, 3), 256, 0, stream>>>(dst[0], dst[1], dst[2],
                                                  E[0], E[1], E[2], cnts);
    k_sa<<<3 * NBK * BINB / 512, 256, 0, stream>>>(cnts, bs);
    k_sb<<<1, 1024, 0, stream>>>(bs, 3 * NBK * BINB / 512);
    k_sc<<<3 * NBK * BINB / 512, 256, 0, stream>>>(cnts, bs);
    k_binplace<<<dim3(BINB, 3), 256, 0, stream>>>(src[0], dst[0], src[1], dst[1],
                                                  src[2], dst[2], E[0], E[1], E[2],
                                                  cnts, ebuf);
    k_build<<<dim3(nbuckets, 3), 256, 0, stream>>>(ebuf, cnts, Etot, E[0], E[1],
                                                   off, cend, rinv,
                                                   nbrg[0], nbrg[1], nbrg[2], N);

    // ---- BN1 stats + fused bf16 conversion of x; bf16 transposed layer-1 weights ----
    k_cs128<<<CSB, 256, 0, stream>>>(x, N, partial, xb);
    k_fin<128><<<128, 256, 0, stream>>>(partial, CSB, N, g1, be1, s1, sh1);
    k_wt<<<dim3(64, 3), 256, 0, stream>>>(W11, W21, W31, WTb);

    // ---- layer 1: 3-graph bf16 gather -> MFMA K=384 GEMM (BN2 stats fused) ----
    const int gblocks = (N + 3) / 4;
    k_gather3<<<dim3(gblocks, 3), 256, 0, stream>>>(xb, nbrg[0], nbrg[1], nbrg[2],
                                                    off, cend, rinv, s1, sh1, AGG3b, N);
    k_gemm1<<<gblocks1, 256, 0, stream>>>(AGG3b, WTb, b11, b21, b31, Hb, partial, N);

    // ---- BN2 finalize; scale folded into W2Tb, shift via c2 ----
    k_fin<128><<<128, 256, 0, stream>>>(partial, gblocks1, N, g2, be2, s2, sh2);
    k_c2<<<3, 256, 0, stream>>>(sh2, W12, W22, W32, c2);
    k_wt2<<<dim3(32, 3), 256, 0, stream>>>(s2, W12, W22, W32, W2Tb);

    // ---- layer 2: MFMA GEMM (bf16 Ub over dead AGG3b), then bf16 gather+combine ----
    dim3 grid2(gblocks1, 3);
    k_gemm2<<<grid2, 256, 0, stream>>>(Hb, W2Tb, c2, Ub, N);
    k_gc64<<<gblocks, 256, 0, stream>>>(Ub, nbrg[0], nbrg[1], nbrg[2], off, cend, rinv,
                                        b12, b22, b32, Z, N);

    // ---- BN3 + epilogue ----
    k_cs64<<<CSB, 256, 0, stream>>>(Z, N, partial);
    k_fin<64><<<64, 256, 0, stream>>>(partial, CSB, N, g3, be3, s3, sh3);
    k_final<<<(N + 3) / 4, 256, 0, stream>>>(Z, s3, sh3, N);
}